// Round 1
// baseline (260.170 us; speedup 1.0000x reference)
//
#include <hip/hip_runtime.h>

// SSIM loss, fused single pass.
// Layout facts: B=16, C=3, H=W=512 -> 48 independent 512x512 fp32 planes per input.
// Separable 11-tap Gaussian; products sr^2/hr^2/sr*hr formed in LDS (no extra HBM reads).

constexpr int IMG_H = 512;
constexpr int IMG_W = 512;
constexpr int NBC   = 48;            // B*C
constexpr int TILE  = 32;            // output tile edge
constexpr int HALO  = 5;             // (11-1)/2
constexpr int ITILE = TILE + 2*HALO; // 42
constexpr int NTAP  = 11;
constexpr float C1 = 1.0e-4f;        // (0.01*MAX_VAL)^2
constexpr float C2 = 9.0e-4f;        // (0.03*MAX_VAL)^2

__global__ __launch_bounds__(256) void ssim_init(double* acc) {
    acc[0] = 0.0;
}

__global__ __launch_bounds__(256) void ssim_main(const float* __restrict__ sr,
                                                 const float* __restrict__ hr,
                                                 double* __restrict__ acc) {
    // LDS: raw tiles (42x42) + 5 horizontal-conv result arrays (42 rows x 32 cols)
    __shared__ float s1[ITILE * ITILE];
    __shared__ float s2[ITILE * ITILE];
    __shared__ float h1 [ITILE * TILE];
    __shared__ float h2 [ITILE * TILE];
    __shared__ float h11[ITILE * TILE];
    __shared__ float h22[ITILE * TILE];
    __shared__ float h12[ITILE * TILE];
    __shared__ float wsums[4];

    // Gaussian weights in registers (match fp32 reference: exp -> normalize)
    float g[NTAP];
    float gsum = 0.f;
    #pragma unroll
    for (int i = 0; i < NTAP; ++i) {
        float d = (float)(i - HALO);
        g[i] = expf(-d * d / (2.0f * 1.5f * 1.5f));
        gsum += g[i];
    }
    #pragma unroll
    for (int i = 0; i < NTAP; ++i) g[i] /= gsum;

    const int bc  = blockIdx.z;
    const int ty0 = blockIdx.y * TILE - HALO; // global row of tile row 0
    const int tx0 = blockIdx.x * TILE - HALO; // global col of tile col 0
    const float* __restrict__ srp = sr + (size_t)bc * IMG_H * IMG_W;
    const float* __restrict__ hrp = hr + (size_t)bc * IMG_H * IMG_W;

    // ---- load 42x42 tiles (zero-padded at image borders) ----
    for (int idx = threadIdx.x; idx < ITILE * ITILE; idx += 256) {
        int r = idx / ITILE, c = idx - r * ITILE;
        int gr = ty0 + r, gc = tx0 + c;
        float a = 0.f, b = 0.f;
        if ((unsigned)gr < (unsigned)IMG_H && (unsigned)gc < (unsigned)IMG_W) {
            size_t o = (size_t)gr * IMG_W + gc;
            a = srp[o];
            b = hrp[o];
        }
        s1[idx] = a;
        s2[idx] = b;
    }
    __syncthreads();

    // ---- horizontal pass: 5 quantities, products formed on the fly ----
    for (int idx = threadIdx.x; idx < ITILE * TILE; idx += 256) {
        int r = idx / TILE, c = idx - r * TILE; // c in [0,32): output col
        const float* p1 = &s1[r * ITILE + c];
        const float* p2 = &s2[r * ITILE + c];
        float a1 = 0.f, a2 = 0.f, a11 = 0.f, a22 = 0.f, a12 = 0.f;
        #pragma unroll
        for (int k = 0; k < NTAP; ++k) {
            float a = p1[k], b = p2[k], gk = g[k];
            float ga = gk * a, gb = gk * b;
            a1  += ga;
            a2  += gb;
            a11 += ga * a;
            a22 += gb * b;
            a12 += ga * b;
        }
        h1 [idx] = a1;
        h2 [idx] = a2;
        h11[idx] = a11;
        h22[idx] = a22;
        h12[idx] = a12;
    }
    __syncthreads();

    // ---- vertical pass + SSIM map + local sum ----
    float local = 0.f;
    for (int idx = threadIdx.x; idx < TILE * TILE; idx += 256) {
        int r = idx / TILE, c = idx - r * TILE;
        float m1 = 0.f, m2 = 0.f, v11 = 0.f, v22 = 0.f, v12 = 0.f;
        #pragma unroll
        for (int k = 0; k < NTAP; ++k) {
            float gk = g[k];
            int ro = (r + k) * TILE + c;
            m1  += gk * h1 [ro];
            m2  += gk * h2 [ro];
            v11 += gk * h11[ro];
            v22 += gk * h22[ro];
            v12 += gk * h12[ro];
        }
        float mu1s = m1 * m1, mu2s = m2 * m2, mu12 = m1 * m2;
        float sg1 = v11 - mu1s, sg2 = v22 - mu2s, sg12 = v12 - mu12;
        float num = (2.f * mu12 + C1) * (2.f * sg12 + C2);
        float den = (mu1s + mu2s + C1) * (sg1 + sg2 + C2) + 1e-12f;
        local += num / den;
    }

    // ---- block reduction: wave shuffle (64 lanes) + cross-wave LDS ----
    #pragma unroll
    for (int off = 32; off > 0; off >>= 1)
        local += __shfl_down(local, off, 64);
    int lane = threadIdx.x & 63, wave = threadIdx.x >> 6;
    if (lane == 0) wsums[wave] = local;
    __syncthreads();
    if (threadIdx.x == 0) {
        float bsum = wsums[0] + wsums[1] + wsums[2] + wsums[3];
        atomicAdd(acc, (double)bsum); // f64 global atomic, one per block
    }
}

__global__ __launch_bounds__(64) void ssim_finalize(const double* __restrict__ acc,
                                                    float* __restrict__ out) {
    if (threadIdx.x == 0) {
        double n = (double)NBC * IMG_H * IMG_W;
        out[0] = (float)(1.0 - acc[0] / n);
    }
}

extern "C" void kernel_launch(void* const* d_in, const int* in_sizes, int n_in,
                              void* d_out, int out_size, void* d_ws, size_t ws_size,
                              hipStream_t stream) {
    const float* sr = (const float*)d_in[0];
    const float* hr = (const float*)d_in[1];
    float* out = (float*)d_out;
    double* acc = (double*)d_ws; // ws is re-poisoned to 0xAA every call -> zero it

    ssim_init<<<dim3(1), dim3(256), 0, stream>>>(acc);
    dim3 grid(IMG_W / TILE, IMG_H / TILE, NBC); // 16 x 16 x 48 = 12288 blocks
    ssim_main<<<grid, dim3(256), 0, stream>>>(sr, hr, acc);
    ssim_finalize<<<dim3(1), dim3(64), 0, stream>>>(acc, out);
}

// Round 2
// 231.073 us; speedup vs baseline: 1.1259x; 1.1259x over previous
//
#include <hip/hip_runtime.h>

// SSIM loss, fused single pass, LDS-vectorized.
// R1 was LDS-issue bound: ~84 ds_read_b32/px = 156us. R2 vectorizes both passes:
//  - h-pass: 4 cols/thread, b128 raw reads (stride 76 aligns the window), b128 h writes
//  - v-pass: 2 cols x 4 rows/thread, register sliding => each h row read once (b64)
// Tile 64x32, LDS 79.3KB -> 2 blocks/CU.

constexpr int IMG_H = 512;
constexpr int IMG_W = 512;
constexpr int NBC   = 48;            // B*C planes
constexpr int TW    = 64;            // tile width  (output)
constexpr int TH    = 32;            // tile height (output)
constexpr int HALO  = 5;
constexpr int NTAP  = 11;
constexpr int IH    = TH + 2*HALO;   // 42 input rows
constexpr int IWR   = TW + 2*HALO;   // 74 input cols
constexpr int SRAW  = 76;            // raw row stride: %4==0 (b128 align), 76%32=12 -> uniform banks
constexpr int SH    = TW;            // 64, h-array row stride (uniform banks for 2-col float2 pattern)
constexpr int NBLKX = IMG_W / TW;    // 8
constexpr int NBLKY = IMG_H / TH;    // 16
constexpr int NBLK  = NBLKX * NBLKY * NBC; // 6144
constexpr float C1 = 1.0e-4f;        // (0.01*MAX_VAL)^2
constexpr float C2 = 9.0e-4f;        // (0.03*MAX_VAL)^2

__device__ __forceinline__ void make_weights(float* g) {
    float gsum = 0.f;
#pragma unroll
    for (int i = 0; i < NTAP; ++i) {
        float d = (float)(i - HALO);
        g[i] = expf(-d * d / (2.0f * 1.5f * 1.5f));
        gsum += g[i];
    }
#pragma unroll
    for (int i = 0; i < NTAP; ++i) g[i] /= gsum;
}

__global__ __launch_bounds__(64) void ssim_init(double* acc) {
    if (threadIdx.x == 0) acc[0] = 0.0;
}

__global__ __launch_bounds__(256, 2) void ssim_main(const float* __restrict__ sr,
                                                    const float* __restrict__ hr,
                                                    double* __restrict__ sink,
                                                    int mode) {
    __shared__ float s1[IH * SRAW];
    __shared__ float s2[IH * SRAW];
    __shared__ float h1 [IH * SH];
    __shared__ float h2 [IH * SH];
    __shared__ float h11[IH * SH];
    __shared__ float h22[IH * SH];
    __shared__ float h12[IH * SH];
    __shared__ float wsums[4];

    float g[NTAP];
    make_weights(g);

    const int bc  = blockIdx.z;
    const int ty0 = blockIdx.y * TH - HALO; // global row of raw tile row 0
    const int tx0 = blockIdx.x * TW - HALO; // global col of raw tile col 0
    const float* __restrict__ srp = sr + (size_t)bc * IMG_H * IMG_W;
    const float* __restrict__ hrp = hr + (size_t)bc * IMG_H * IMG_W;

    // ---- load raw tiles (zero pad at borders AND in the stride-pad cols) ----
    for (int idx = threadIdx.x; idx < IH * SRAW; idx += 256) {
        const int r = idx / SRAW, l = idx - r * SRAW;
        const int gr = ty0 + r, gc = tx0 + l;
        float a = 0.f, b = 0.f;
        if (l < IWR && (unsigned)gr < (unsigned)IMG_H && (unsigned)gc < (unsigned)IMG_W) {
            const size_t o = (size_t)gr * IMG_W + gc;
            a = srp[o];
            b = hrp[o];
        }
        s1[idx] = a;
        s2[idx] = b;
    }
    __syncthreads();

    // ---- horizontal pass: thread task = 1 row x 4 output cols, b128 in/out ----
    // h[r][c] = sum_k g[k] * raw[r][c+k]  (raw col c+k maps to global tx0+c+k)
    for (int tt = threadIdx.x; tt < IH * (TW / 4); tt += 256) { // 42*16 = 672 tasks
        const int r  = tt >> 4;
        const int c0 = (tt & 15) << 2;
        const float* base1 = &s1[r * SRAW + c0];
        const float* base2 = &s2[r * SRAW + c0];
        float a[16], b[16];
        *(float4*)&a[0]  = *(const float4*)&base1[0];
        *(float4*)&a[4]  = *(const float4*)&base1[4];
        *(float4*)&a[8]  = *(const float4*)&base1[8];
        *(float4*)&a[12] = *(const float4*)&base1[12];
        *(float4*)&b[0]  = *(const float4*)&base2[0];
        *(float4*)&b[4]  = *(const float4*)&base2[4];
        *(float4*)&b[8]  = *(const float4*)&base2[8];
        *(float4*)&b[12] = *(const float4*)&base2[12];
        float q11[14], q22[14], q12[14];
#pragma unroll
        for (int j = 0; j < 14; ++j) {
            q11[j] = a[j] * a[j];
            q22[j] = b[j] * b[j];
            q12[j] = a[j] * b[j];
        }
        float o1[4], o2[4], o11[4], o22[4], o12[4];
#pragma unroll
        for (int i = 0; i < 4; ++i) {
            float t1 = 0.f, t2 = 0.f, t11 = 0.f, t22 = 0.f, t12 = 0.f;
#pragma unroll
            for (int k = 0; k < NTAP; ++k) {
                const float gk = g[k];
                t1  += gk * a[i + k];
                t2  += gk * b[i + k];
                t11 += gk * q11[i + k];
                t22 += gk * q22[i + k];
                t12 += gk * q12[i + k];
            }
            o1[i] = t1; o2[i] = t2; o11[i] = t11; o22[i] = t22; o12[i] = t12;
        }
        const int ho = r * SH + c0;
        *(float4*)&h1 [ho] = make_float4(o1 [0], o1 [1], o1 [2], o1 [3]);
        *(float4*)&h2 [ho] = make_float4(o2 [0], o2 [1], o2 [2], o2 [3]);
        *(float4*)&h11[ho] = make_float4(o11[0], o11[1], o11[2], o11[3]);
        *(float4*)&h22[ho] = make_float4(o22[0], o22[1], o22[2], o22[3]);
        *(float4*)&h12[ho] = make_float4(o12[0], o12[1], o12[2], o12[3]);
    }
    __syncthreads();

    // ---- vertical pass: thread = 2 cols x 4 rows, sliding over 14 h-rows ----
    // out[r] = sum_k g[k]*h[r+k]; h-row r0+j feeds outputs i with i<=j<=i+10, tap g[j-i]
    float local = 0.f;
    {
        const int t  = threadIdx.x;
        const int c0 = (t & 31) * 2;
        const int r0 = (t >> 5) * 4;
        float A1[4][2] = {}, A2[4][2] = {}, A11[4][2] = {}, A22[4][2] = {}, A12[4][2] = {};
#pragma unroll
        for (int j = 0; j < 14; ++j) {
            const int ho = (r0 + j) * SH + c0;
            const float2 x1  = *(const float2*)&h1 [ho];
            const float2 x2  = *(const float2*)&h2 [ho];
            const float2 x11 = *(const float2*)&h11[ho];
            const float2 x22 = *(const float2*)&h22[ho];
            const float2 x12 = *(const float2*)&h12[ho];
#pragma unroll
            for (int i = 0; i < 4; ++i) {
                if (j >= i && j <= i + 10) {
                    const float gk = g[j - i];
                    A1 [i][0] += gk * x1.x;  A1 [i][1] += gk * x1.y;
                    A2 [i][0] += gk * x2.x;  A2 [i][1] += gk * x2.y;
                    A11[i][0] += gk * x11.x; A11[i][1] += gk * x11.y;
                    A22[i][0] += gk * x22.x; A22[i][1] += gk * x22.y;
                    A12[i][0] += gk * x12.x; A12[i][1] += gk * x12.y;
                }
            }
        }
#pragma unroll
        for (int i = 0; i < 4; ++i) {
#pragma unroll
            for (int u = 0; u < 2; ++u) {
                const float m1 = A1[i][u], m2 = A2[i][u];
                const float mu1s = m1 * m1, mu2s = m2 * m2, mu12 = m1 * m2;
                const float sg1  = A11[i][u] - mu1s;
                const float sg2  = A22[i][u] - mu2s;
                const float sg12 = A12[i][u] - mu12;
                const float num = (2.f * mu12 + C1) * (2.f * sg12 + C2);
                const float den = (mu1s + mu2s + C1) * (sg1 + sg2 + C2) + 1e-12f;
                local += num / den;
            }
        }
    }

    // ---- block reduction ----
#pragma unroll
    for (int off = 32; off > 0; off >>= 1)
        local += __shfl_down(local, off, 64);
    const int lane = threadIdx.x & 63, wave = threadIdx.x >> 6;
    if (lane == 0) wsums[wave] = local;
    __syncthreads();
    if (threadIdx.x == 0) {
        const double bsum = (double)(wsums[0] + wsums[1] + wsums[2] + wsums[3]);
        if (mode == 0) {
            const int bid = (blockIdx.z * NBLKY + blockIdx.y) * NBLKX + blockIdx.x;
            sink[bid] = bsum;
        } else {
            atomicAdd(sink, bsum);
        }
    }
}

__global__ __launch_bounds__(256) void ssim_finalize(const double* __restrict__ partial,
                                                     float* __restrict__ out, int count) {
    __shared__ double ws[4];
    double s = 0.0;
    for (int i = threadIdx.x; i < count; i += 256) s += partial[i];
#pragma unroll
    for (int off = 32; off > 0; off >>= 1)
        s += __shfl_down(s, off, 64);
    const int lane = threadIdx.x & 63, wave = threadIdx.x >> 6;
    if (lane == 0) ws[wave] = s;
    __syncthreads();
    if (threadIdx.x == 0) {
        const double tot = ws[0] + ws[1] + ws[2] + ws[3];
        const double n = (double)NBC * IMG_H * IMG_W;
        out[0] = (float)(1.0 - tot / n);
    }
}

extern "C" void kernel_launch(void* const* d_in, const int* in_sizes, int n_in,
                              void* d_out, int out_size, void* d_ws, size_t ws_size,
                              hipStream_t stream) {
    const float* sr = (const float*)d_in[0];
    const float* hr = (const float*)d_in[1];
    float* out = (float*)d_out;
    const dim3 grid(NBLKX, NBLKY, NBC);

    if (ws_size >= (size_t)NBLK * sizeof(double)) {
        double* partial = (double*)d_ws; // fully overwritten each call; no init needed
        ssim_main<<<grid, dim3(256), 0, stream>>>(sr, hr, partial, 0);
        ssim_finalize<<<dim3(1), dim3(256), 0, stream>>>(partial, out, NBLK);
    } else {
        double* acc = (double*)d_ws;
        ssim_init<<<dim3(1), dim3(64), 0, stream>>>(acc);
        ssim_main<<<grid, dim3(256), 0, stream>>>(sr, hr, acc, 1);
        ssim_finalize<<<dim3(1), dim3(256), 0, stream>>>(acc, out, 1);
    }
}